// Round 8
// baseline (794.299 us; speedup 1.0000x reference)
//
#include <hip/hip_runtime.h>
#include <hip/hip_bf16.h>

#define BATCH 16
#define NN 1024
#define MM 1024
#define DD 512

#define LOG2E 1.4426950408889634f
#define LN2f  0.6931471805599453f
#define NEGS  -1.442695e9f   // NEG (-1e9) scaled by log2e; acts as -inf sentinel

#define DSTAG 144             // inter-wave column stagger (73-iter write->read gap > BARP)
#define BARP  64              // barrier period (iters)
#define GTOT  1520            // >= 1023 + 3*DSTAG + 63 + 1 = 1519, multiple of 8
#define PF    8               // prefetch depth (iterations) for theta and ring

typedef __bf16 v8bf __attribute__((ext_vector_type(8)));
typedef __bf16 v4bf __attribute__((ext_vector_type(4)));
typedef float  v4f  __attribute__((ext_vector_type(4)));

// DPP wave shift-right by 1: lane i <- lane i-1 (full-rate VALU, no LDS).
// Lane 0 keeps its own value (bound_ctrl=0, old=src) — always fixed up after.
__device__ __forceinline__ float wave_shr1(float x) {
    int xi = __float_as_int(x);
    int r = __builtin_amdgcn_update_dpp(xi, xi, 0x138, 0xf, 0xf, false);
    return __int_as_float(r);
}

// ---------------------------------------------------------------- zero A acc
__global__ void zero_acc(float* a) {
    if (threadIdx.x < BATCH) a[threadIdx.x] = 0.0f;
}

// ------------------------------------------- fp32->bf16 convert + gap-dot
__global__ __launch_bounds__(256) void conv_reduce(
        const float* __restrict__ zx, const float* __restrict__ zy,
        const float* __restrict__ gw,
        __bf16* __restrict__ zxb, __bf16* __restrict__ zyb,
        float* __restrict__ acc) {
    const int chunk = blockIdx.x, b = blockIdx.y, which = blockIdx.z;
    const float* src = which ? zy : zx;
    __bf16* dst = which ? zyb : zxb;
    const float* g = gw + which * DD;
    const size_t base = ((size_t)b * NN + (size_t)chunk * 64) * DD;
    const int t = threadIdx.x;
    const int col = (t * 4) & (DD - 1);
    const float4 gv = *(const float4*)(g + col);
    float sum = 0.0f;
    #pragma unroll 4
    for (int it = 0; it < 32; ++it) {
        size_t off = base + (size_t)it * 1024 + t * 4;
        float4 x = *(const float4*)(src + off);
        sum += x.x * gv.x + x.y * gv.y + x.z * gv.z + x.w * gv.w;
        v4bf o = { (__bf16)x.x, (__bf16)x.y, (__bf16)x.z, (__bf16)x.w };
        *(v4bf*)(dst + off) = o;
    }
    #pragma unroll
    for (int o = 32; o > 0; o >>= 1) sum += __shfl_down(sum, o);
    __shared__ float wsum[4];
    if ((t & 63) == 0) wsum[t >> 6] = sum;
    __syncthreads();
    if (t == 0) {
        float s = wsum[0] + wsum[1] + wsum[2] + wsum[3];
        atomicAdd(acc + b, s * (1.0f / 1024.0f));
    }
}

// ------------------------------------------------------- bf16 MFMA NT GEMM
// out[row i][col j] = sum_d A[i,d]*B[j,d].  Called with A=zyb, B=zxb so the
// output buffer is thetaT[j_theta][i_theta] (theta transposed) at zero cost.
__global__ __launch_bounds__(256) void gemm_bt(
        const __bf16* __restrict__ Abf, const __bf16* __restrict__ Bbf,
        float* __restrict__ theta) {
    __shared__ __bf16 As[64 * 40];
    __shared__ __bf16 Bs[64 * 40];
    const int b = blockIdx.z;
    const int i0 = blockIdx.y * 64, j0 = blockIdx.x * 64;
    const __bf16* ap = Abf + ((size_t)b * NN + i0) * DD;
    const __bf16* bp = Bbf + ((size_t)b * MM + j0) * DD;
    const int t = threadIdx.x;
    const int srow = t >> 2, scol = (t & 3) * 8;
    const int lane = t & 63, wave = t >> 6;
    const int mrow = lane & 15, quad = lane >> 4;
    v4f acc[4] = {};
    for (int kk = 0; kk < DD; kk += 32) {
        if (kk) __syncthreads();
        *(v8bf*)&As[srow * 40 + scol] = *(const v8bf*)(ap + (size_t)srow * DD + kk + scol);
        *(v8bf*)&Bs[srow * 40 + scol] = *(const v8bf*)(bp + (size_t)srow * DD + kk + scol);
        __syncthreads();
        v8bf af = *(const v8bf*)&As[(wave * 16 + mrow) * 40 + quad * 8];
        #pragma unroll
        for (int tt = 0; tt < 4; ++tt) {
            v8bf bf = *(const v8bf*)&Bs[(tt * 16 + mrow) * 40 + quad * 8];
            acc[tt] = __builtin_amdgcn_mfma_f32_16x16x32_bf16(af, bf, acc[tt], 0, 0, 0);
        }
    }
    const size_t tb = (size_t)b * NN * MM;
    #pragma unroll
    for (int tt = 0; tt < 4; ++tt) {
        int j = j0 + tt * 16 + mrow;
        #pragma unroll
        for (int r = 0; r < 4; ++r) {
            int i = i0 + wave * 16 + quad * 4 + r;
            theta[tb + (size_t)i * MM + j] = acc[tt][r];
        }
    }
}

// --------------------------------------------------- soft-NW wavefront DP
// TWO independent batches per block (512 thr): waves 0-3 -> batch 2*blk,
// waves 4-7 -> batch 2*blk+1. Each SIMD hosts two waves with INDEPENDENT
// chains -> issue of one fills chain stalls of the other.
// Within a group: wave wg owns V-rows 256wg+1..256wg+256, lane t owns 4 rows,
// stagger DSTAG=144 cols, barrier every 64 iters. Ring values prefetched
// 8 iters ahead (write->read gap 73 > 64 => one barrier always orders them).
// Cross-lane handoff: one DPP wave_shr:1; tp is previous iter's tc.
// Theta: 8-deep circular register prefetch (unroll-by-8), exact R6 math.
__global__ __launch_bounds__(512) void nw_dp(
        const float* __restrict__ thetaT, const float* __restrict__ acc,
        const float* __restrict__ gap_b, float* __restrict__ out) {
    const int tid = threadIdx.x;
    const int t = tid & 63, w = tid >> 6;
    const int grp = w >> 2, wg = w & 3;
    const int b = blockIdx.x * 2 + grp;
    const float Ac = (acc[b] + gap_b[0]) * LOG2E;
    const int row0 = wg * 256 + t * 4;         // theta rows row0..row0+3
    const int off = wg * DSTAG + t;            // lane's column lag
    const float* Tb = thetaT + (size_t)b * NN * MM + row0;

    __shared__ float ring[2][3][256];

    float v[4];
    v[0] = v[1] = v[2] = v[3] = NEGS;
    float vbc = NEGS, vbp = NEGS;              // bottom-row value, iter-1 / iter-2

    float4 pf[PF];
    #pragma unroll
    for (int u = 0; u < PF; ++u) {
        int c0 = u - off;
        c0 = c0 < 0 ? 0 : (c0 > MM - 1 ? MM - 1 : c0);
        pf[u] = *(const float4*)(Tb + (size_t)c0 * NN);
    }
    float rt[PF];                              // ring prefetch regs (lane0, wg>0)
    #pragma unroll
    for (int u = 0; u < PF; ++u) rt[u] = NEGS;
    float rtprev = NEGS;

    for (int gg = 0; gg < GTOT; gg += PF) {
        #pragma unroll
        for (int u = 0; u < PF; ++u) {
            const int g = gg + u;
            const int c = g - off;
            float tc = wave_shr1(vbc);
            float tp = wave_shr1(vbp);
            if (t == 0) {
                if (wg == 0) { tc = NEGS; tp = (c == 0) ? 0.0f : NEGS; }
                else         { tc = rt[u]; tp = (c == 0) ? NEGS : rtprev; rtprev = rt[u]; }
            }
            vbp = vbc;

            const float4 cur = pf[u];
            int cn = g + PF - off;
            cn = cn < 0 ? 0 : (cn > MM - 1 ? MM - 1 : cn);
            pf[u] = *(const float4*)(Tb + (size_t)cn * NN);

            if (c >= 0 && c < MM) {
                const float* th = (const float*)&cur;
                float up_in = tc, dg = tp;
                #pragma unroll
                for (int k = 0; k < 4; ++k) {
                    float left = v[k];
                    float up = up_in + Ac;
                    float lf = left + Ac;
                    float mx = fmaxf(fmaxf(up, dg), lf);
                    float ss = __builtin_amdgcn_exp2f(up - mx)
                             + __builtin_amdgcn_exp2f(dg - mx)
                             + __builtin_amdgcn_exp2f(lf - mx);
                    float nv = fmaf(th[k], LOG2E, mx + __builtin_amdgcn_logf(ss));
                    dg = left;      // next row's diag = V[row][jc-1]
                    up_in = nv;     // next row's up   = V[row][jc]
                    v[k] = nv;
                }
                vbc = v[3];
                if (t == 63 && wg < 3) ring[grp][wg][c & 255] = v[3];
            }

            if ((g & (BARP - 1)) == (BARP - 1)) __syncthreads();

            // ring prefetch for iteration g+PF (after the barrier; producer
            // wrote column g+PF-off 73 iterations before its consumption).
            if (t == 0 && wg > 0) {
                int cp = g + PF - off;
                cp = cp < 0 ? 0 : (cp > MM - 1 ? MM - 1 : cp);
                rt[u] = ring[grp][wg - 1][cp & 255];
            }
        }
    }
    if (t == 63 && wg == 3) out[b] = v[3] * LN2f;
}

// ---------------------------------------------------------------- launcher
extern "C" void kernel_launch(void* const* d_in, const int* in_sizes, int n_in,
                              void* d_out, int out_size, void* d_ws, size_t ws_size,
                              hipStream_t stream) {
    const float* zx    = (const float*)d_in[0];
    const float* zy    = (const float*)d_in[1];
    const float* gw    = (const float*)d_in[2];
    const float* gapb  = (const float*)d_in[3];
    float* out = (float*)d_out;

    char* ws = (char*)d_ws;
    float*  thetaT = (float*)ws;                                  // 67,108,864 B
    __bf16* zxb   = (__bf16*)(ws + (size_t)67108864);             // 16,777,216 B
    __bf16* zyb   = (__bf16*)(ws + (size_t)67108864 + 16777216);  // 16,777,216 B
    float*  acc   = (float*)(ws + (size_t)67108864 + 2 * 16777216);

    zero_acc<<<1, 64, 0, stream>>>(acc);
    conv_reduce<<<dim3(16, BATCH, 2), 256, 0, stream>>>(zx, zy, gw, zxb, zyb, acc);
    // swapped args: output = theta^T
    gemm_bt<<<dim3(MM / 64, NN / 64, BATCH), 256, 0, stream>>>(zyb, zxb, thetaT);
    nw_dp<<<BATCH / 2, 512, 0, stream>>>(thetaT, acc, gapb, out);
}

// Round 9
// 531.683 us; speedup vs baseline: 1.4939x; 1.4939x over previous
//
#include <hip/hip_runtime.h>
#include <hip/hip_bf16.h>

#define BATCH 16
#define NN 1024
#define MM 1024
#define DD 512

#define LOG2E 1.4426950408889634f
#define LN2f  0.6931471805599453f
#define NEGS  -1.442695e9f   // NEG (-1e9) scaled by log2e; acts as -inf sentinel

#define DSTAG 144             // inter-wave column stagger (73-iter write->read gap > BARP)
#define BARP  64              // barrier period (iters)
#define GTOT  1520            // >= 1023 + 3*DSTAG + 63 + 1 = 1519, multiple of 8
#define PF    8               // prefetch depth (iterations) for theta and ring

typedef __bf16 v8bf __attribute__((ext_vector_type(8)));
typedef __bf16 v4bf __attribute__((ext_vector_type(4)));
typedef float  v4f  __attribute__((ext_vector_type(4)));

// DPP wave shift-right by 1: lane i <- lane i-1 (full-rate VALU, no LDS).
// Lane 0 keeps its own value (bound_ctrl=0, old=src) — always fixed up after.
// Verified correct (absmax 0) in R8.
__device__ __forceinline__ float wave_shr1(float x) {
    int xi = __float_as_int(x);
    int r = __builtin_amdgcn_update_dpp(xi, xi, 0x138, 0xf, 0xf, false);
    return __int_as_float(r);
}

// ---------------------------------------------------------------- zero A acc
__global__ void zero_acc(float* a) {
    if (threadIdx.x < BATCH) a[threadIdx.x] = 0.0f;
}

// ------------------------------------------- fp32->bf16 convert + gap-dot
__global__ __launch_bounds__(256) void conv_reduce(
        const float* __restrict__ zx, const float* __restrict__ zy,
        const float* __restrict__ gw,
        __bf16* __restrict__ zxb, __bf16* __restrict__ zyb,
        float* __restrict__ acc) {
    const int chunk = blockIdx.x, b = blockIdx.y, which = blockIdx.z;
    const float* src = which ? zy : zx;
    __bf16* dst = which ? zyb : zxb;
    const float* g = gw + which * DD;
    const size_t base = ((size_t)b * NN + (size_t)chunk * 64) * DD;
    const int t = threadIdx.x;
    const int col = (t * 4) & (DD - 1);
    const float4 gv = *(const float4*)(g + col);
    float sum = 0.0f;
    #pragma unroll 4
    for (int it = 0; it < 32; ++it) {
        size_t off = base + (size_t)it * 1024 + t * 4;
        float4 x = *(const float4*)(src + off);
        sum += x.x * gv.x + x.y * gv.y + x.z * gv.z + x.w * gv.w;
        v4bf o = { (__bf16)x.x, (__bf16)x.y, (__bf16)x.z, (__bf16)x.w };
        *(v4bf*)(dst + off) = o;
    }
    #pragma unroll
    for (int o = 32; o > 0; o >>= 1) sum += __shfl_down(sum, o);
    __shared__ float wsum[4];
    if ((t & 63) == 0) wsum[t >> 6] = sum;
    __syncthreads();
    if (t == 0) {
        float s = wsum[0] + wsum[1] + wsum[2] + wsum[3];
        atomicAdd(acc + b, s * (1.0f / 1024.0f));
    }
}

// ------------------------------------------------------- bf16 MFMA NT GEMM
// out[row i][col j] = sum_d A[i,d]*B[j,d].  Called with A=zyb, B=zxb so the
// output buffer is thetaT[j_theta][i_theta] (theta transposed) at zero cost.
__global__ __launch_bounds__(256) void gemm_bt(
        const __bf16* __restrict__ Abf, const __bf16* __restrict__ Bbf,
        float* __restrict__ theta) {
    __shared__ __bf16 As[64 * 40];
    __shared__ __bf16 Bs[64 * 40];
    const int b = blockIdx.z;
    const int i0 = blockIdx.y * 64, j0 = blockIdx.x * 64;
    const __bf16* ap = Abf + ((size_t)b * NN + i0) * DD;
    const __bf16* bp = Bbf + ((size_t)b * MM + j0) * DD;
    const int t = threadIdx.x;
    const int srow = t >> 2, scol = (t & 3) * 8;
    const int lane = t & 63, wave = t >> 6;
    const int mrow = lane & 15, quad = lane >> 4;
    v4f acc[4] = {};
    for (int kk = 0; kk < DD; kk += 32) {
        if (kk) __syncthreads();
        *(v8bf*)&As[srow * 40 + scol] = *(const v8bf*)(ap + (size_t)srow * DD + kk + scol);
        *(v8bf*)&Bs[srow * 40 + scol] = *(const v8bf*)(bp + (size_t)srow * DD + kk + scol);
        __syncthreads();
        v8bf af = *(const v8bf*)&As[(wave * 16 + mrow) * 40 + quad * 8];
        #pragma unroll
        for (int tt = 0; tt < 4; ++tt) {
            v8bf bf = *(const v8bf*)&Bs[(tt * 16 + mrow) * 40 + quad * 8];
            acc[tt] = __builtin_amdgcn_mfma_f32_16x16x32_bf16(af, bf, acc[tt], 0, 0, 0);
        }
    }
    const size_t tb = (size_t)b * NN * MM;
    #pragma unroll
    for (int tt = 0; tt < 4; ++tt) {
        int j = j0 + tt * 16 + mrow;
        #pragma unroll
        for (int r = 0; r < 4; ++r) {
            int i = i0 + wave * 16 + quad * 4 + r;
            theta[tb + (size_t)i * MM + j] = acc[tt][r];
        }
    }
}

// --------------------------------------------------- soft-NW wavefront DP
// R6 structure (best measured): 1 batch per 256-thr block, 4 waves, 1/SIMD.
// Wave w owns V-rows 256w+1..256w+256, lane t owns 4 rows, stagger DSTAG=144,
// barrier every 64 iters. Three latency cuts vs R6:
//  - DPP wave_shr:1 handoff (no ds_bpermute)          [verified R8]
//  - ring prefetched PF=8 iters ahead, 1 ds_read/iter [verified R8]
//  - ss = 1 + e(med-mx) + e(min-mx): bitwise-identical lse (one term is
//    e(mx-mx)=1), one fewer v_exp_f32 per cell.
__global__ __launch_bounds__(256) void nw_dp(
        const float* __restrict__ thetaT, const float* __restrict__ acc,
        const float* __restrict__ gap_b, float* __restrict__ out) {
    const int tid = threadIdx.x;
    const int t = tid & 63, w = tid >> 6;
    const int b = blockIdx.x;
    const float Ac = (acc[b] + gap_b[0]) * LOG2E;
    const int row0 = w * 256 + t * 4;          // theta rows row0..row0+3
    const int off = w * DSTAG + t;             // lane's column lag
    const float* Tb = thetaT + (size_t)b * NN * MM + row0;

    __shared__ float ring[3][256];

    float v[4];
    v[0] = v[1] = v[2] = v[3] = NEGS;
    float vbc = NEGS, vbp = NEGS;              // bottom-row value, iter-1 / iter-2

    float4 pf[PF];
    #pragma unroll
    for (int u = 0; u < PF; ++u) {
        int c0 = u - off;
        c0 = c0 < 0 ? 0 : (c0 > MM - 1 ? MM - 1 : c0);
        pf[u] = *(const float4*)(Tb + (size_t)c0 * NN);
    }
    float rt[PF];                              // ring prefetch regs (lane0, w>0)
    #pragma unroll
    for (int u = 0; u < PF; ++u) rt[u] = NEGS;
    float rtprev = NEGS;

    for (int gg = 0; gg < GTOT; gg += PF) {
        #pragma unroll
        for (int u = 0; u < PF; ++u) {
            const int g = gg + u;
            const int c = g - off;
            float tc = wave_shr1(vbc);
            float tp = wave_shr1(vbp);
            if (t == 0) {
                if (w == 0) { tc = NEGS; tp = (c == 0) ? 0.0f : NEGS; }
                else        { tc = rt[u]; tp = (c == 0) ? NEGS : rtprev; rtprev = rt[u]; }
            }
            vbp = vbc;

            const float4 cur = pf[u];
            int cn = g + PF - off;
            cn = cn < 0 ? 0 : (cn > MM - 1 ? MM - 1 : cn);
            pf[u] = *(const float4*)(Tb + (size_t)cn * NN);

            if (c >= 0 && c < MM) {
                const float* th = (const float*)&cur;
                float up_in = tc, dg = tp;
                #pragma unroll
                for (int k = 0; k < 4; ++k) {
                    float left = v[k];
                    float up = up_in + Ac;
                    float lf = left + Ac;
                    float mx = fmaxf(fmaxf(up, dg), lf);              // v_max3
                    float md = __builtin_amdgcn_fmed3f(up, dg, lf);   // v_med3
                    float mn = fminf(fminf(up, dg), lf);              // v_min3
                    float ss = 1.0f + (__builtin_amdgcn_exp2f(md - mx)
                                     + __builtin_amdgcn_exp2f(mn - mx));
                    float nv = fmaf(th[k], LOG2E, mx + __builtin_amdgcn_logf(ss));
                    dg = left;      // next row's diag = V[row][jc-1]
                    up_in = nv;     // next row's up   = V[row][jc]
                    v[k] = nv;
                }
                vbc = v[3];
                if (t == 63 && w < 3) ring[w][c & 255] = v[3];
            }

            if ((g & (BARP - 1)) == (BARP - 1)) __syncthreads();

            // ring prefetch for iteration g+PF (after the barrier; producer
            // wrote column g+PF-off 73 iterations before its consumption).
            if (t == 0 && w > 0) {
                int cp = g + PF - off;
                cp = cp < 0 ? 0 : (cp > MM - 1 ? MM - 1 : cp);
                rt[u] = ring[w - 1][cp & 255];
            }
        }
    }
    if (t == 63 && w == 3) out[b] = v[3] * LN2f;
}

// ---------------------------------------------------------------- launcher
extern "C" void kernel_launch(void* const* d_in, const int* in_sizes, int n_in,
                              void* d_out, int out_size, void* d_ws, size_t ws_size,
                              hipStream_t stream) {
    const float* zx    = (const float*)d_in[0];
    const float* zy    = (const float*)d_in[1];
    const float* gw    = (const float*)d_in[2];
    const float* gapb  = (const float*)d_in[3];
    float* out = (float*)d_out;

    char* ws = (char*)d_ws;
    float*  thetaT = (float*)ws;                                  // 67,108,864 B
    __bf16* zxb   = (__bf16*)(ws + (size_t)67108864);             // 16,777,216 B
    __bf16* zyb   = (__bf16*)(ws + (size_t)67108864 + 16777216);  // 16,777,216 B
    float*  acc   = (float*)(ws + (size_t)67108864 + 2 * 16777216);

    zero_acc<<<1, 64, 0, stream>>>(acc);
    conv_reduce<<<dim3(16, BATCH, 2), 256, 0, stream>>>(zx, zy, gw, zxb, zyb, acc);
    // swapped args: output = theta^T
    gemm_bt<<<dim3(MM / 64, NN / 64, BATCH), 256, 0, stream>>>(zyb, zxb, thetaT);
    nw_dp<<<BATCH, 256, 0, stream>>>(thetaT, acc, gapb, out);
}